// Round 5
// baseline (1840.227 us; speedup 1.0000x reference)
//
#include <hip/hip_runtime.h>
#include <hip/hip_bf16.h>

#define NN 20000
#define NE 640000

__device__ __forceinline__ float silu_f(float x) {
    return x / (1.0f + __expf(-x));
}

__device__ __forceinline__ unsigned int f2bf_bits(float f) {
    __hip_bfloat16 b = __float2bfloat16(f);
    return (unsigned int)*(unsigned short*)&b;
}

// ---------------------------------------------------------------------------
// Kernel A1: per-node y precompute. PLANE-MAJOR layout:
//   yrow[v]            = y0[v]
//   yrow[32 + m*32+v]  = y1[v][m]   (m=0..2)
//   yrow[128 + m*32+v] = y2[v][m]   (m=0..4)
// so gather_reduce reads are lane-coalesced. block = 8 nodes x 32 ch.
// ---------------------------------------------------------------------------
__global__ __launch_bounds__(256) void node_y(
    const float* __restrict__ x,
    const float* __restrict__ W10,
    const float* __restrict__ W11,
    const float* __restrict__ W12,
    float* __restrict__ yAll)
{
    __shared__ float xs[8][288];
    __shared__ float w10[1024];
    __shared__ float w11[1024];
    __shared__ float w12[1024];
    const int tid = threadIdx.x;
    const int nodeBase = blockIdx.x * 8;

    for (int i = tid; i < 1024; i += 256) { w10[i] = W10[i]; w11[i] = W11[i]; w12[i] = W12[i]; }
    for (int i = tid; i < 8 * 288; i += 256) {
        int nl = i / 288, c = i % 288;
        int n = nodeBase + nl;
        xs[nl][c] = (n < NN) ? x[(long)n * 288 + c] : 0.f;
    }
    __syncthreads();

    const int nl = tid >> 5, v = tid & 31;
    const int n = nodeBase + nl;
    if (n >= NN) return;

    const float inv_mul = 0.17677669529663687f;  // 1/sqrt(32)
    float* yrow = yAll + (long)n * 288;

    {
        float a = 0.f;
        #pragma unroll
        for (int u = 0; u < 32; ++u) a += xs[nl][u] * w10[u * 32 + v];
        yrow[v] = a * inv_mul;
    }
    {
        float a0 = 0.f, a1 = 0.f, a2 = 0.f;
        #pragma unroll
        for (int u = 0; u < 32; ++u) {
            float wv = w11[u * 32 + v];
            a0 += xs[nl][32 + u * 3 + 0] * wv;
            a1 += xs[nl][32 + u * 3 + 1] * wv;
            a2 += xs[nl][32 + u * 3 + 2] * wv;
        }
        yrow[32 + 0 * 32 + v] = a0 * inv_mul;
        yrow[32 + 1 * 32 + v] = a1 * inv_mul;
        yrow[32 + 2 * 32 + v] = a2 * inv_mul;
    }
    {
        float a[5] = {0.f, 0.f, 0.f, 0.f, 0.f};
        #pragma unroll
        for (int u = 0; u < 32; ++u) {
            float wv = w12[u * 32 + v];
            #pragma unroll
            for (int m = 0; m < 5; ++m) a[m] += xs[nl][128 + u * 5 + m] * wv;
        }
        #pragma unroll
        for (int m = 0; m < 5; ++m) yrow[128 + m * 32 + v] = a[m] * inv_mul;
    }
}

// ---------------------------------------------------------------------------
// Kernel A2: sc GEMM. 64 nodes/block; thread = 8 nodes x 3 cols.
// ---------------------------------------------------------------------------
__global__ __launch_bounds__(256) void node_sc(
    const float* __restrict__ x,
    const float* __restrict__ na,
    const float* __restrict__ scW,
    float* __restrict__ sc)
{
    __shared__ float B[128 * 96];
    __shared__ float x0s[64 * 32];
    __shared__ float nas[64 * 4];
    const int tid = threadIdx.x;
    const int nodeBase = blockIdx.x * 64;

    for (int i = tid; i < 12288; i += 256) {
        int h = i >> 12, r = i & 4095;
        int u = r >> 7, r2 = r & 127;
        int t = r2 >> 5, w = r2 & 31;
        B[(u * 4 + t) * 96 + h * 32 + w] = scW[i];
    }
    for (int i = tid; i < 2048; i += 256) {
        int nl = i >> 5, u = i & 31;
        int n = nodeBase + nl;
        x0s[i] = (n < NN) ? x[(long)n * 288 + u] : 0.f;
    }
    for (int i = tid; i < 256; i += 256) {
        int nl = i >> 2, t = i & 3;
        int n = nodeBase + nl;
        nas[i] = (n < NN) ? na[n * 4 + t] : 0.f;
    }
    __syncthreads();

    const int g = tid >> 5, c = tid & 31;
    float nav[8][4];
    #pragma unroll
    for (int j = 0; j < 8; ++j)
        #pragma unroll
        for (int t = 0; t < 4; ++t) nav[j][t] = nas[(g * 8 + j) * 4 + t];

    float acc[3][8];
    #pragma unroll
    for (int cc = 0; cc < 3; ++cc)
        #pragma unroll
        for (int j = 0; j < 8; ++j) acc[cc][j] = 0.f;

    for (int u = 0; u < 32; ++u) {
        float aj[8];
        #pragma unroll
        for (int j = 0; j < 8; ++j) aj[j] = x0s[(g * 8 + j) * 32 + u];
        #pragma unroll
        for (int t = 0; t < 4; ++t) {
            float b0 = B[(u * 4 + t) * 96 + c];
            float b1 = B[(u * 4 + t) * 96 + 32 + c];
            float b2 = B[(u * 4 + t) * 96 + 64 + c];
            #pragma unroll
            for (int j = 0; j < 8; ++j) {
                float p = aj[j] * nav[j][t];
                acc[0][j] += p * b0;
                acc[1][j] += p * b1;
                acc[2][j] += p * b2;
            }
        }
    }

    const float inv_sc = 0.08838834764831845f;  // 1/sqrt(128)
    #pragma unroll
    for (int j = 0; j < 8; ++j) {
        int n = nodeBase + g * 8 + j;
        if (n < NN) {
            #pragma unroll
            for (int cc = 0; cc < 3; ++cc)
                sc[((long)cc * NN + n) * 32 + c] = acc[cc][j] * inv_sc;
        }
    }
}

// ---------------------------------------------------------------------------
// CSR build: histogram -> scan -> scatter ids (+ rank of each edge).
// ---------------------------------------------------------------------------
__global__ __launch_bounds__(256) void hist_kernel(
    const int* __restrict__ ei, int* __restrict__ counts)
{
    int e = blockIdx.x * 256 + threadIdx.x;
    if (e < NE) atomicAdd(&counts[ei[NE + e]], 1);
}

__global__ __launch_bounds__(1024) void scan_kernel(
    const int* __restrict__ counts, int* __restrict__ offsets)
{
    __shared__ int partial[1024];
    const int t = threadIdx.x;
    const int base = t * 20;          // 1024*20 = 20480 >= NN
    int loc[20];
    int s = 0;
    #pragma unroll
    for (int i = 0; i < 20; ++i) {
        int v = (base + i < NN) ? counts[base + i] : 0;
        loc[i] = s;
        s += v;
    }
    partial[t] = s;
    __syncthreads();
    for (int off = 1; off < 1024; off <<= 1) {
        int v = (t >= off) ? partial[t - off] : 0;
        __syncthreads();
        partial[t] += v;
        __syncthreads();
    }
    int pre = (t == 0) ? 0 : partial[t - 1];
    #pragma unroll
    for (int i = 0; i < 20; ++i)
        if (base + i <= NN) offsets[base + i] = pre + loc[i];
}

__global__ __launch_bounds__(256) void scatter_ids(
    const int* __restrict__ ei, const int* __restrict__ offsets,
    int* __restrict__ cursor, int* __restrict__ sidx, int* __restrict__ rank)
{
    int e = blockIdx.x * 256 + threadIdx.x;
    if (e < NE) {
        int d = ei[NE + e];
        int pos = offsets[d] + atomicAdd(&cursor[d], 1);
        sidx[pos] = e;
        rank[e] = pos;
    }
}

// ---------------------------------------------------------------------------
// Kernel B1: w = silu(ee@Wm0/sqrt8) @ Wm1 / sqrt64. NATURAL edge order
// (coalesced ee staging — R2's proven body). Output: packed bf16x2 rows
// (48 uints/row), scatter-written to sorted position rank[e]. Stores are
// 4B/lane via shfl_xor pairing -> full-line coverage, no sub-dword stores.
// ---------------------------------------------------------------------------
__global__ __launch_bounds__(256) void edge_w(
    const float* __restrict__ ee,
    const float* __restrict__ Wm0,
    const float* __restrict__ Wm1,
    const int*   __restrict__ rank,
    unsigned int* __restrict__ w)
{
    __shared__ float wm0s[512];        // [k*64 + i]
    __shared__ float wm1t[96 * 68];    // [c*68 + k]
    __shared__ float ees[64 * 8];      // [e*8 + k]
    __shared__ float hs[64 * 68];      // [e*68 + k]
    __shared__ int   rnk[64];
    const int tid = threadIdx.x;
    const int eb = blockIdx.x * 64;    // natural edge base

    for (int i = tid; i < 512; i += 256) wm0s[i] = Wm0[i];
    for (int i = tid; i < 6144; i += 256) {
        int k = i / 96, c = i % 96;
        wm1t[c * 68 + k] = Wm1[i];
    }
    for (int i = tid; i < 512; i += 256) ees[i] = ee[(long)eb * 8 + i];
    if (tid < 64) rnk[tid] = rank[eb + tid];
    __syncthreads();

    // phase 1: h
    {
        const float inv_sqrt8 = 0.35355339059327373f;
        const int e = tid >> 2, i0 = (tid & 3) * 16;
        float emb[8];
        #pragma unroll
        for (int k = 0; k < 8; ++k) emb[k] = ees[e * 8 + k];
        #pragma unroll
        for (int i = 0; i < 16; ++i) {
            float t = 0.f;
            #pragma unroll
            for (int k = 0; k < 8; ++k) t += emb[k] * wm0s[k * 64 + i0 + i];
            hs[e * 68 + i0 + i] = silu_f(t * inv_sqrt8);
        }
    }
    __syncthreads();

    // phase 2: thread (g,u) -> edges g*8..g*8+7, channels {u, u+32, u+64}
    const int u = tid & 31, g = tid >> 5;
    float acc[3][8];
    #pragma unroll
    for (int cc = 0; cc < 3; ++cc)
        #pragma unroll
        for (int j = 0; j < 8; ++j) acc[cc][j] = 0.f;

    #pragma unroll
    for (int k = 0; k < 64; k += 4) {
        float4 wv0 = *(const float4*)&wm1t[u * 68 + k];
        float4 wv1 = *(const float4*)&wm1t[(u + 32) * 68 + k];
        float4 wv2 = *(const float4*)&wm1t[(u + 64) * 68 + k];
        #pragma unroll
        for (int j = 0; j < 8; ++j) {
            float4 hv = *(const float4*)&hs[(g * 8 + j) * 68 + k];
            acc[0][j] += hv.x * wv0.x + hv.y * wv0.y + hv.z * wv0.z + hv.w * wv0.w;
            acc[1][j] += hv.x * wv1.x + hv.y * wv1.y + hv.z * wv1.z + hv.w * wv1.w;
            acc[2][j] += hv.x * wv2.x + hv.y * wv2.y + hv.z * wv2.z + hv.w * wv2.w;
        }
    }

    // epilogue: pair channels (2p, 2p+1) via shfl_xor, even lanes store uint.
    // row layout: pair p of channel c=2p,2p+1 at wrow[p]; c=u block base:
    //   cc=0 -> pairs [0,16), cc=1 -> [16,32), cc=2 -> [32,48)
    const bool evenLane = ((u & 1) == 0);
    #pragma unroll
    for (int j = 0; j < 8; ++j) {
        long row = (long)rnk[g * 8 + j] * 48;
        #pragma unroll
        for (int cc = 0; cc < 3; ++cc) {
            float mine  = acc[cc][j] * 0.125f;           // fold 1/sqrt(HID)
            float other = __shfl_xor(mine, 1);
            if (evenLane) {
                unsigned int lo = f2bf_bits(mine);        // even channel -> low
                unsigned int hi = f2bf_bits(other);       // odd channel -> high
                w[row + cc * 16 + (u >> 1)] = lo | (hi << 16);
            }
        }
    }
}

// ---------------------------------------------------------------------------
// Kernel B2: single-pass atomic-free gather-reduce. 32-lane group owns node
// n; w read SEQUENTIALLY (sorted rows), yAll plane-major -> all loads
// lane-coalesced. Register accumulate, one store of mid per node.
// ---------------------------------------------------------------------------
__global__ __launch_bounds__(256) void gather_reduce(
    const unsigned int* __restrict__ w,
    const float* __restrict__ ea,
    const int*   __restrict__ ei,
    const float* __restrict__ yAll,
    const int*   __restrict__ sidx,
    const int*   __restrict__ offsets,
    float* __restrict__ mid)
{
    const int tid = threadIdx.x;
    const int n = blockIdx.x * 8 + (tid >> 5);
    const int u = tid & 31;
    if (n >= NN) return;

    const int lo = offsets[n], hi = offsets[n + 1];

    const float invAVG = 0.17677669529663687f;                        // 1/sqrt(32)
    const float c1     = 0.5773502691896258f * 0.17677669529663687f;  // /sqrt3/sqrt32
    const float c2     = 0.4472135954999579f * 0.17677669529663687f;  // /sqrt5/sqrt32

    const int p = u >> 1;
    const bool odd = (u & 1);

    float acc0 = 0.f, acc1 = 0.f, acc2 = 0.f;
    #pragma unroll 2
    for (int j = lo; j < hi; ++j) {
        const int e = sidx[j];                 // broadcast within group
        const int s = ei[e];                   // broadcast
        const unsigned int* wr = w + (long)j * 48;
        const float* eav = ea + (long)e * 9;
        const float* yb  = yAll + (long)s * 288;

        unsigned int v0 = wr[p];
        unsigned int v1 = wr[16 + p];
        unsigned int v2 = wr[32 + p];
        float w0 = odd ? __uint_as_float(v0 & 0xffff0000u) : __uint_as_float(v0 << 16);
        float w1 = odd ? __uint_as_float(v1 & 0xffff0000u) : __uint_as_float(v1 << 16);
        float w2 = odd ? __uint_as_float(v2 & 0xffff0000u) : __uint_as_float(v2 << 16);

        acc0 += w0 * yb[u] * eav[0];

        float d1 = yb[32 + 0 * 32 + u] * eav[1]
                 + yb[32 + 1 * 32 + u] * eav[2]
                 + yb[32 + 2 * 32 + u] * eav[3];
        acc1 += w1 * d1;

        float d2 = yb[128 + 0 * 32 + u] * eav[4]
                 + yb[128 + 1 * 32 + u] * eav[5]
                 + yb[128 + 2 * 32 + u] * eav[6]
                 + yb[128 + 3 * 32 + u] * eav[7]
                 + yb[128 + 4 * 32 + u] * eav[8];
        acc2 += w2 * d2;
    }

    float* midRow = mid + (long)n * 96;
    midRow[u]      = acc0 * invAVG;
    midRow[32 + u] = acc1 * c1;
    midRow[64 + u] = acc2 * c2;
}

// ---------------------------------------------------------------------------
// Kernel C: output GEMV + sc + silu.
// ---------------------------------------------------------------------------
__global__ __launch_bounds__(256) void node_out(
    const float* __restrict__ mid,
    const float* __restrict__ sc,
    const float* __restrict__ L0,
    const float* __restrict__ L1,
    const float* __restrict__ L2,
    float* __restrict__ out)
{
    __shared__ float l0[32 * 32];
    __shared__ float l1[64 * 32];
    __shared__ float l2[96 * 32];
    __shared__ float ms[8][96];
    const int tid = threadIdx.x;
    const int nodeBase = blockIdx.x * 8;

    for (int i = tid; i < 1024; i += 256) l0[i] = L0[i];
    for (int i = tid; i < 2048; i += 256) l1[i] = L1[i];
    for (int i = tid; i < 3072; i += 256) l2[i] = L2[i];
    for (int i = tid; i < 768; i += 256) {
        int nl = i / 96, c = i % 96;
        int n = nodeBase + nl;
        ms[nl][c] = (n < NN) ? mid[(long)n * 96 + c] : 0.f;
    }
    __syncthreads();

    const int nl = tid >> 5, wv = tid & 31;
    const int n = nodeBase + nl;
    if (n >= NN) return;

    float a0 = 0.f, a1 = 0.f, a2 = 0.f;
    #pragma unroll
    for (int u = 0; u < 32; ++u) {
        float m = ms[nl][u];
        a0 += m * l0[u * 32 + wv];
        a1 += m * l1[u * 32 + wv];
        a2 += m * l2[u * 32 + wv];
    }
    #pragma unroll
    for (int u = 32; u < 64; ++u) {
        float m = ms[nl][u];
        a1 += m * l1[u * 32 + wv];
        a2 += m * l2[u * 32 + wv];
    }
    #pragma unroll
    for (int u = 64; u < 96; ++u) a2 += ms[nl][u] * l2[u * 32 + wv];

    const float is32 = 0.17677669529663687f;
    const float is64 = 0.125f;
    const float is96 = 0.10206207261596575f;
    const long base = (long)n * 32 + wv;
    out[base]                     = silu_f(a0 * is32 + sc[base]);
    out[(long)NN * 32 + base]     = silu_f(a1 * is64 + sc[(long)NN * 32 + base]);
    out[(long)2 * NN * 32 + base] = silu_f(a2 * is96 + sc[(long)2 * NN * 32 + base]);
}

extern "C" void kernel_launch(void* const* d_in, const int* in_sizes, int n_in,
                              void* d_out, int out_size, void* d_ws, size_t ws_size,
                              hipStream_t stream)
{
    const float* x   = (const float*)d_in[0];
    const float* na  = (const float*)d_in[1];
    const float* ee  = (const float*)d_in[2];
    const float* ea  = (const float*)d_in[3];
    const int*   ei  = (const int*)d_in[4];
    const float* W10 = (const float*)d_in[5];
    const float* W11 = (const float*)d_in[6];
    const float* W12 = (const float*)d_in[7];
    const float* Wm0 = (const float*)d_in[8];
    const float* Wm1 = (const float*)d_in[9];
    const float* L0  = (const float*)d_in[10];
    const float* L1  = (const float*)d_in[11];
    const float* L2  = (const float*)d_in[12];
    const float* scW = (const float*)d_in[13];
    float* out = (float*)d_out;

    float* yAll    = (float*)d_ws;                  // NN*288 f32
    float* sc      = yAll + (size_t)NN * 288;       // 3*NN*32 f32
    float* mid     = sc + (size_t)3 * NN * 32;      // NN*96 f32
    int*   counts  = (int*)(mid + (size_t)NN * 96); // NN
    int*   offsets = counts + NN;                   // NN+1
    int*   cursor  = offsets + NN + 1;              // NN
    int*   sidx    = cursor + NN;                   // NE
    int*   rank    = sidx + NE;                     // NE
    unsigned int* wbuf = (unsigned int*)(rank + NE);// NE*48 uints (123 MB)

    hipMemsetAsync(counts, 0, NN * sizeof(int), stream);
    hipMemsetAsync(cursor, 0, NN * sizeof(int), stream);

    hist_kernel<<<(NE + 255) / 256, 256, 0, stream>>>(ei, counts);
    scan_kernel<<<1, 1024, 0, stream>>>(counts, offsets);
    scatter_ids<<<(NE + 255) / 256, 256, 0, stream>>>(ei, offsets, cursor, sidx, rank);

    node_y<<<(NN + 7) / 8, 256, 0, stream>>>(x, W10, W11, W12, yAll);
    node_sc<<<(NN + 63) / 64, 256, 0, stream>>>(x, na, scW, sc);

    edge_w<<<NE / 64, 256, 0, stream>>>(ee, Wm0, Wm1, rank, wbuf);
    gather_reduce<<<(NN + 7) / 8, 256, 0, stream>>>(wbuf, ea, ei, yAll, sidx,
                                                    offsets, mid);

    node_out<<<(NN + 7) / 8, 256, 0, stream>>>(mid, sc, L0, L1, L2, out);
}

// Round 6
// 583.256 us; speedup vs baseline: 3.1551x; 3.1551x over previous
//
#include <hip/hip_runtime.h>
#include <hip/hip_bf16.h>

#define NN 20000
#define NE 640000

__device__ __forceinline__ float silu_f(float x) {
    return x / (1.0f + __expf(-x));
}

__device__ __forceinline__ unsigned int f2bf_bits(float f) {
    __hip_bfloat16 b = __float2bfloat16(f);
    return (unsigned int)*(unsigned short*)&b;
}

// ---------------------------------------------------------------------------
// Kernel A1: per-node y precompute. PLANE-MAJOR layout:
//   yrow[v]            = y0[v]
//   yrow[32 + m*32+v]  = y1[v][m]   (m=0..2)
//   yrow[128 + m*32+v] = y2[v][m]   (m=0..4)
// ---------------------------------------------------------------------------
__global__ __launch_bounds__(256) void node_y(
    const float* __restrict__ x,
    const float* __restrict__ W10,
    const float* __restrict__ W11,
    const float* __restrict__ W12,
    float* __restrict__ yAll)
{
    __shared__ float xs[8][288];
    __shared__ float w10[1024];
    __shared__ float w11[1024];
    __shared__ float w12[1024];
    const int tid = threadIdx.x;
    const int nodeBase = blockIdx.x * 8;

    for (int i = tid; i < 1024; i += 256) { w10[i] = W10[i]; w11[i] = W11[i]; w12[i] = W12[i]; }
    for (int i = tid; i < 8 * 288; i += 256) {
        int nl = i / 288, c = i % 288;
        int n = nodeBase + nl;
        xs[nl][c] = (n < NN) ? x[(long)n * 288 + c] : 0.f;
    }
    __syncthreads();

    const int nl = tid >> 5, v = tid & 31;
    const int n = nodeBase + nl;
    if (n >= NN) return;

    const float inv_mul = 0.17677669529663687f;  // 1/sqrt(32)
    float* yrow = yAll + (long)n * 288;

    {
        float a = 0.f;
        #pragma unroll
        for (int u = 0; u < 32; ++u) a += xs[nl][u] * w10[u * 32 + v];
        yrow[v] = a * inv_mul;
    }
    {
        float a0 = 0.f, a1 = 0.f, a2 = 0.f;
        #pragma unroll
        for (int u = 0; u < 32; ++u) {
            float wv = w11[u * 32 + v];
            a0 += xs[nl][32 + u * 3 + 0] * wv;
            a1 += xs[nl][32 + u * 3 + 1] * wv;
            a2 += xs[nl][32 + u * 3 + 2] * wv;
        }
        yrow[32 + 0 * 32 + v] = a0 * inv_mul;
        yrow[32 + 1 * 32 + v] = a1 * inv_mul;
        yrow[32 + 2 * 32 + v] = a2 * inv_mul;
    }
    {
        float a[5] = {0.f, 0.f, 0.f, 0.f, 0.f};
        #pragma unroll
        for (int u = 0; u < 32; ++u) {
            float wv = w12[u * 32 + v];
            #pragma unroll
            for (int m = 0; m < 5; ++m) a[m] += xs[nl][128 + u * 5 + m] * wv;
        }
        #pragma unroll
        for (int m = 0; m < 5; ++m) yrow[128 + m * 32 + v] = a[m] * inv_mul;
    }
}

// ---------------------------------------------------------------------------
// Kernel A2: sc GEMM. 64 nodes/block; thread = 8 nodes x 3 cols.
// ---------------------------------------------------------------------------
__global__ __launch_bounds__(256) void node_sc(
    const float* __restrict__ x,
    const float* __restrict__ na,
    const float* __restrict__ scW,
    float* __restrict__ sc)
{
    __shared__ float B[128 * 96];
    __shared__ float x0s[64 * 32];
    __shared__ float nas[64 * 4];
    const int tid = threadIdx.x;
    const int nodeBase = blockIdx.x * 64;

    for (int i = tid; i < 12288; i += 256) {
        int h = i >> 12, r = i & 4095;
        int u = r >> 7, r2 = r & 127;
        int t = r2 >> 5, w = r2 & 31;
        B[(u * 4 + t) * 96 + h * 32 + w] = scW[i];
    }
    for (int i = tid; i < 2048; i += 256) {
        int nl = i >> 5, u = i & 31;
        int n = nodeBase + nl;
        x0s[i] = (n < NN) ? x[(long)n * 288 + u] : 0.f;
    }
    for (int i = tid; i < 256; i += 256) {
        int nl = i >> 2, t = i & 3;
        int n = nodeBase + nl;
        nas[i] = (n < NN) ? na[n * 4 + t] : 0.f;
    }
    __syncthreads();

    const int g = tid >> 5, c = tid & 31;
    float nav[8][4];
    #pragma unroll
    for (int j = 0; j < 8; ++j)
        #pragma unroll
        for (int t = 0; t < 4; ++t) nav[j][t] = nas[(g * 8 + j) * 4 + t];

    float acc[3][8];
    #pragma unroll
    for (int cc = 0; cc < 3; ++cc)
        #pragma unroll
        for (int j = 0; j < 8; ++j) acc[cc][j] = 0.f;

    for (int u = 0; u < 32; ++u) {
        float aj[8];
        #pragma unroll
        for (int j = 0; j < 8; ++j) aj[j] = x0s[(g * 8 + j) * 32 + u];
        #pragma unroll
        for (int t = 0; t < 4; ++t) {
            float b0 = B[(u * 4 + t) * 96 + c];
            float b1 = B[(u * 4 + t) * 96 + 32 + c];
            float b2 = B[(u * 4 + t) * 96 + 64 + c];
            #pragma unroll
            for (int j = 0; j < 8; ++j) {
                float p = aj[j] * nav[j][t];
                acc[0][j] += p * b0;
                acc[1][j] += p * b1;
                acc[2][j] += p * b2;
            }
        }
    }

    const float inv_sc = 0.08838834764831845f;  // 1/sqrt(128)
    #pragma unroll
    for (int j = 0; j < 8; ++j) {
        int n = nodeBase + g * 8 + j;
        if (n < NN) {
            #pragma unroll
            for (int cc = 0; cc < 3; ++cc)
                sc[((long)cc * NN + n) * 32 + c] = acc[cc][j] * inv_sc;
        }
    }
}

// ---------------------------------------------------------------------------
// CSR build: histogram -> scan -> scatter ids.
// ---------------------------------------------------------------------------
__global__ __launch_bounds__(256) void hist_kernel(
    const int* __restrict__ ei, int* __restrict__ counts)
{
    int e = blockIdx.x * 256 + threadIdx.x;
    if (e < NE) atomicAdd(&counts[ei[NE + e]], 1);
}

__global__ __launch_bounds__(1024) void scan_kernel(
    const int* __restrict__ counts, int* __restrict__ offsets)
{
    __shared__ int partial[1024];
    const int t = threadIdx.x;
    const int base = t * 20;          // 1024*20 = 20480 >= NN
    int loc[20];
    int s = 0;
    #pragma unroll
    for (int i = 0; i < 20; ++i) {
        int v = (base + i < NN) ? counts[base + i] : 0;
        loc[i] = s;
        s += v;
    }
    partial[t] = s;
    __syncthreads();
    for (int off = 1; off < 1024; off <<= 1) {
        int v = (t >= off) ? partial[t - off] : 0;
        __syncthreads();
        partial[t] += v;
        __syncthreads();
    }
    int pre = (t == 0) ? 0 : partial[t - 1];
    #pragma unroll
    for (int i = 0; i < 20; ++i)
        if (base + i <= NN) offsets[base + i] = pre + loc[i];
}

__global__ __launch_bounds__(256) void scatter_ids(
    const int* __restrict__ ei, const int* __restrict__ offsets,
    int* __restrict__ cursor, int* __restrict__ sidx)
{
    int e = blockIdx.x * 256 + threadIdx.x;
    if (e < NE) {
        int d = ei[NE + e];
        int pos = offsets[d] + atomicAdd(&cursor[d], 1);
        sidx[pos] = e;
    }
}

// ---------------------------------------------------------------------------
// Kernel B1: w = silu(ee@Wm0/sqrt8) @ Wm1 / sqrt64. NATURAL edge order,
// CONTIGUOUS output at natural edge position (no rank, no guard: NE%64==0).
// bf16x2-packed rows (48 uints). k-loop unroll limited to 4 to cap VGPR
// pressure (R4/R5 hit the 256-VGPR cap and spilled ~1.2 KB/thread to
// scratch -> GBs of HBM traffic).
// ---------------------------------------------------------------------------
__global__ __launch_bounds__(256) void edge_w(
    const float* __restrict__ ee,
    const float* __restrict__ Wm0,
    const float* __restrict__ Wm1,
    unsigned int* __restrict__ w)
{
    __shared__ float wm0s[512];        // [k*64 + i]
    __shared__ float wm1t[96 * 68];    // [c*68 + k]
    __shared__ float ees[64 * 8];      // [e*8 + k]
    __shared__ float hs[64 * 68];      // [e*68 + k]
    const int tid = threadIdx.x;
    const int eb = blockIdx.x * 64;    // natural edge base

    for (int i = tid; i < 512; i += 256) wm0s[i] = Wm0[i];
    for (int i = tid; i < 6144; i += 256) {
        int k = i / 96, c = i % 96;
        wm1t[c * 68 + k] = Wm1[i];
    }
    for (int i = tid; i < 512; i += 256) ees[i] = ee[(long)eb * 8 + i];
    __syncthreads();

    // phase 1: h
    {
        const float inv_sqrt8 = 0.35355339059327373f;
        const int e = tid >> 2, i0 = (tid & 3) * 16;
        float emb[8];
        #pragma unroll
        for (int k = 0; k < 8; ++k) emb[k] = ees[e * 8 + k];
        #pragma unroll
        for (int i = 0; i < 16; ++i) {
            float t = 0.f;
            #pragma unroll
            for (int k = 0; k < 8; ++k) t += emb[k] * wm0s[k * 64 + i0 + i];
            hs[e * 68 + i0 + i] = silu_f(t * inv_sqrt8);
        }
    }
    __syncthreads();

    // phase 2: thread (g,u) -> edges g*8..g*8+7, channels {u, u+32, u+64}
    const int u = tid & 31, g = tid >> 5;
    float acc[3][8];
    #pragma unroll
    for (int cc = 0; cc < 3; ++cc)
        #pragma unroll
        for (int j = 0; j < 8; ++j) acc[cc][j] = 0.f;

    #pragma unroll 4
    for (int k = 0; k < 64; k += 4) {
        float4 wv0 = *(const float4*)&wm1t[u * 68 + k];
        float4 wv1 = *(const float4*)&wm1t[(u + 32) * 68 + k];
        float4 wv2 = *(const float4*)&wm1t[(u + 64) * 68 + k];
        #pragma unroll
        for (int j = 0; j < 8; ++j) {
            float4 hv = *(const float4*)&hs[(g * 8 + j) * 68 + k];
            acc[0][j] += hv.x * wv0.x + hv.y * wv0.y + hv.z * wv0.z + hv.w * wv0.w;
            acc[1][j] += hv.x * wv1.x + hv.y * wv1.y + hv.z * wv1.z + hv.w * wv1.w;
            acc[2][j] += hv.x * wv2.x + hv.y * wv2.y + hv.z * wv2.z + hv.w * wv2.w;
        }
    }

    // epilogue: pair channels (2p,2p+1) via shfl_xor; even lanes store one
    // uint. Row = natural edge id -> contiguous 64B segments per (j,cc).
    const bool evenLane = ((u & 1) == 0);
    #pragma unroll
    for (int j = 0; j < 8; ++j) {
        long row = (long)(eb + g * 8 + j) * 48;
        #pragma unroll
        for (int cc = 0; cc < 3; ++cc) {
            float mine  = acc[cc][j] * 0.125f;           // fold 1/sqrt(HID)
            float other = __shfl_xor(mine, 1);
            if (evenLane) {
                unsigned int lo = f2bf_bits(mine);        // even channel -> low
                unsigned int hi = f2bf_bits(other);       // odd channel -> high
                w[row + cc * 16 + (u >> 1)] = lo | (hi << 16);
            }
        }
    }
}

// ---------------------------------------------------------------------------
// Kernel B2: single-pass atomic-free gather-reduce. 32-lane group owns node
// n; w rows indexed by EDGE ID (natural layout). yAll plane-major -> all
// loads lane-coalesced. Register accumulate, one store of mid per node.
// ---------------------------------------------------------------------------
__global__ __launch_bounds__(256) void gather_reduce(
    const unsigned int* __restrict__ w,
    const float* __restrict__ ea,
    const int*   __restrict__ ei,
    const float* __restrict__ yAll,
    const int*   __restrict__ sidx,
    const int*   __restrict__ offsets,
    float* __restrict__ mid)
{
    const int tid = threadIdx.x;
    const int n = blockIdx.x * 8 + (tid >> 5);
    const int u = tid & 31;
    if (n >= NN) return;

    const int lo = offsets[n], hi = offsets[n + 1];

    const float invAVG = 0.17677669529663687f;                        // 1/sqrt(32)
    const float c1     = 0.5773502691896258f * 0.17677669529663687f;  // /sqrt3/sqrt32
    const float c2     = 0.4472135954999579f * 0.17677669529663687f;  // /sqrt5/sqrt32

    const int p = u >> 1;
    const bool odd = (u & 1);

    float acc0 = 0.f, acc1 = 0.f, acc2 = 0.f;
    #pragma unroll 2
    for (int j = lo; j < hi; ++j) {
        const int e = sidx[j];                 // broadcast within group
        const int s = ei[e];                   // broadcast
        const unsigned int* wr = w + (long)e * 48;
        const float* eav = ea + (long)e * 9;
        const float* yb  = yAll + (long)s * 288;

        unsigned int v0 = wr[p];
        unsigned int v1 = wr[16 + p];
        unsigned int v2 = wr[32 + p];
        float w0 = odd ? __uint_as_float(v0 & 0xffff0000u) : __uint_as_float(v0 << 16);
        float w1 = odd ? __uint_as_float(v1 & 0xffff0000u) : __uint_as_float(v1 << 16);
        float w2 = odd ? __uint_as_float(v2 & 0xffff0000u) : __uint_as_float(v2 << 16);

        acc0 += w0 * yb[u] * eav[0];

        float d1 = yb[32 + 0 * 32 + u] * eav[1]
                 + yb[32 + 1 * 32 + u] * eav[2]
                 + yb[32 + 2 * 32 + u] * eav[3];
        acc1 += w1 * d1;

        float d2 = yb[128 + 0 * 32 + u] * eav[4]
                 + yb[128 + 1 * 32 + u] * eav[5]
                 + yb[128 + 2 * 32 + u] * eav[6]
                 + yb[128 + 3 * 32 + u] * eav[7]
                 + yb[128 + 4 * 32 + u] * eav[8];
        acc2 += w2 * d2;
    }

    float* midRow = mid + (long)n * 96;
    midRow[u]      = acc0 * invAVG;
    midRow[32 + u] = acc1 * c1;
    midRow[64 + u] = acc2 * c2;
}

// ---------------------------------------------------------------------------
// Kernel C: output GEMV + sc + silu.
// ---------------------------------------------------------------------------
__global__ __launch_bounds__(256) void node_out(
    const float* __restrict__ mid,
    const float* __restrict__ sc,
    const float* __restrict__ L0,
    const float* __restrict__ L1,
    const float* __restrict__ L2,
    float* __restrict__ out)
{
    __shared__ float l0[32 * 32];
    __shared__ float l1[64 * 32];
    __shared__ float l2[96 * 32];
    __shared__ float ms[8][96];
    const int tid = threadIdx.x;
    const int nodeBase = blockIdx.x * 8;

    for (int i = tid; i < 1024; i += 256) l0[i] = L0[i];
    for (int i = tid; i < 2048; i += 256) l1[i] = L1[i];
    for (int i = tid; i < 3072; i += 256) l2[i] = L2[i];
    for (int i = tid; i < 768; i += 256) {
        int nl = i / 96, c = i % 96;
        int n = nodeBase + nl;
        ms[nl][c] = (n < NN) ? mid[(long)n * 96 + c] : 0.f;
    }
    __syncthreads();

    const int nl = tid >> 5, wv = tid & 31;
    const int n = nodeBase + nl;
    if (n >= NN) return;

    float a0 = 0.f, a1 = 0.f, a2 = 0.f;
    #pragma unroll
    for (int u = 0; u < 32; ++u) {
        float m = ms[nl][u];
        a0 += m * l0[u * 32 + wv];
        a1 += m * l1[u * 32 + wv];
        a2 += m * l2[u * 32 + wv];
    }
    #pragma unroll
    for (int u = 32; u < 64; ++u) {
        float m = ms[nl][u];
        a1 += m * l1[u * 32 + wv];
        a2 += m * l2[u * 32 + wv];
    }
    #pragma unroll
    for (int u = 64; u < 96; ++u) a2 += ms[nl][u] * l2[u * 32 + wv];

    const float is32 = 0.17677669529663687f;
    const float is64 = 0.125f;
    const float is96 = 0.10206207261596575f;
    const long base = (long)n * 32 + wv;
    out[base]                     = silu_f(a0 * is32 + sc[base]);
    out[(long)NN * 32 + base]     = silu_f(a1 * is64 + sc[(long)NN * 32 + base]);
    out[(long)2 * NN * 32 + base] = silu_f(a2 * is96 + sc[(long)2 * NN * 32 + base]);
}

extern "C" void kernel_launch(void* const* d_in, const int* in_sizes, int n_in,
                              void* d_out, int out_size, void* d_ws, size_t ws_size,
                              hipStream_t stream)
{
    const float* x   = (const float*)d_in[0];
    const float* na  = (const float*)d_in[1];
    const float* ee  = (const float*)d_in[2];
    const float* ea  = (const float*)d_in[3];
    const int*   ei  = (const int*)d_in[4];
    const float* W10 = (const float*)d_in[5];
    const float* W11 = (const float*)d_in[6];
    const float* W12 = (const float*)d_in[7];
    const float* Wm0 = (const float*)d_in[8];
    const float* Wm1 = (const float*)d_in[9];
    const float* L0  = (const float*)d_in[10];
    const float* L1  = (const float*)d_in[11];
    const float* L2  = (const float*)d_in[12];
    const float* scW = (const float*)d_in[13];
    float* out = (float*)d_out;

    float* yAll    = (float*)d_ws;                  // NN*288 f32
    float* sc      = yAll + (size_t)NN * 288;       // 3*NN*32 f32
    float* mid     = sc + (size_t)3 * NN * 32;      // NN*96 f32
    int*   counts  = (int*)(mid + (size_t)NN * 96); // NN
    int*   offsets = counts + NN;                   // NN+1
    int*   cursor  = offsets + NN + 1;              // NN
    int*   sidx    = cursor + NN;                   // NE
    unsigned int* wbuf = (unsigned int*)(sidx + NE);// NE*48 uints (123 MB)

    hipMemsetAsync(counts, 0, NN * sizeof(int), stream);
    hipMemsetAsync(cursor, 0, NN * sizeof(int), stream);

    hist_kernel<<<(NE + 255) / 256, 256, 0, stream>>>(ei, counts);
    scan_kernel<<<1, 1024, 0, stream>>>(counts, offsets);
    scatter_ids<<<(NE + 255) / 256, 256, 0, stream>>>(ei, offsets, cursor, sidx);

    node_y<<<(NN + 7) / 8, 256, 0, stream>>>(x, W10, W11, W12, yAll);
    node_sc<<<(NN + 63) / 64, 256, 0, stream>>>(x, na, scW, sc);

    edge_w<<<NE / 64, 256, 0, stream>>>(ee, Wm0, Wm1, wbuf);
    gather_reduce<<<(NN + 7) / 8, 256, 0, stream>>>(wbuf, ea, ei, yAll, sidx,
                                                    offsets, mid);

    node_out<<<(NN + 7) / 8, 256, 0, stream>>>(mid, sc, L0, L1, L2, out);
}

// Round 7
// 502.733 us; speedup vs baseline: 3.6604x; 1.1602x over previous
//
#include <hip/hip_runtime.h>
#include <hip/hip_bf16.h>

#define NN 20000
#define NE 640000

typedef __attribute__((ext_vector_type(8))) short short8v;   // 8 bf16
typedef __attribute__((ext_vector_type(4))) float float4v;

__device__ __forceinline__ float silu_f(float x) {
    return x / (1.0f + __expf(-x));
}

__device__ __forceinline__ unsigned short f2bf16(float f) {
    __hip_bfloat16 b = __float2bfloat16(f);
    return *(unsigned short*)&b;
}

// ---------------------------------------------------------------------------
// Kernel A1: per-node y precompute. PLANE-MAJOR layout:
//   yrow[v]; yrow[32+m*32+v] (m<3); yrow[128+m*32+v] (m<5)
// ---------------------------------------------------------------------------
__global__ __launch_bounds__(256) void node_y(
    const float* __restrict__ x,
    const float* __restrict__ W10,
    const float* __restrict__ W11,
    const float* __restrict__ W12,
    float* __restrict__ yAll)
{
    __shared__ float xs[8][288];
    __shared__ float w10[1024];
    __shared__ float w11[1024];
    __shared__ float w12[1024];
    const int tid = threadIdx.x;
    const int nodeBase = blockIdx.x * 8;

    for (int i = tid; i < 1024; i += 256) { w10[i] = W10[i]; w11[i] = W11[i]; w12[i] = W12[i]; }
    for (int i = tid; i < 8 * 288; i += 256) {
        int nl = i / 288, c = i % 288;
        int n = nodeBase + nl;
        xs[nl][c] = (n < NN) ? x[(long)n * 288 + c] : 0.f;
    }
    __syncthreads();

    const int nl = tid >> 5, v = tid & 31;
    const int n = nodeBase + nl;
    if (n >= NN) return;

    const float inv_mul = 0.17677669529663687f;  // 1/sqrt(32)
    float* yrow = yAll + (long)n * 288;

    {
        float a = 0.f;
        #pragma unroll
        for (int u = 0; u < 32; ++u) a += xs[nl][u] * w10[u * 32 + v];
        yrow[v] = a * inv_mul;
    }
    {
        float a0 = 0.f, a1 = 0.f, a2 = 0.f;
        #pragma unroll
        for (int u = 0; u < 32; ++u) {
            float wv = w11[u * 32 + v];
            a0 += xs[nl][32 + u * 3 + 0] * wv;
            a1 += xs[nl][32 + u * 3 + 1] * wv;
            a2 += xs[nl][32 + u * 3 + 2] * wv;
        }
        yrow[32 + 0 * 32 + v] = a0 * inv_mul;
        yrow[32 + 1 * 32 + v] = a1 * inv_mul;
        yrow[32 + 2 * 32 + v] = a2 * inv_mul;
    }
    {
        float a[5] = {0.f, 0.f, 0.f, 0.f, 0.f};
        #pragma unroll
        for (int u = 0; u < 32; ++u) {
            float wv = w12[u * 32 + v];
            #pragma unroll
            for (int m = 0; m < 5; ++m) a[m] += xs[nl][128 + u * 5 + m] * wv;
        }
        #pragma unroll
        for (int m = 0; m < 5; ++m) yrow[128 + m * 32 + v] = a[m] * inv_mul;
    }
}

// ---------------------------------------------------------------------------
// Kernel A2: sc GEMM. 64 nodes/block; thread = 8 nodes x 3 cols.
// ---------------------------------------------------------------------------
__global__ __launch_bounds__(256) void node_sc(
    const float* __restrict__ x,
    const float* __restrict__ na,
    const float* __restrict__ scW,
    float* __restrict__ sc)
{
    __shared__ float B[128 * 96];
    __shared__ float x0s[64 * 32];
    __shared__ float nas[64 * 4];
    const int tid = threadIdx.x;
    const int nodeBase = blockIdx.x * 64;

    for (int i = tid; i < 12288; i += 256) {
        int h = i >> 12, r = i & 4095;
        int u = r >> 7, r2 = r & 127;
        int t = r2 >> 5, w = r2 & 31;
        B[(u * 4 + t) * 96 + h * 32 + w] = scW[i];
    }
    for (int i = tid; i < 2048; i += 256) {
        int nl = i >> 5, u = i & 31;
        int n = nodeBase + nl;
        x0s[i] = (n < NN) ? x[(long)n * 288 + u] : 0.f;
    }
    for (int i = tid; i < 256; i += 256) {
        int nl = i >> 2, t = i & 3;
        int n = nodeBase + nl;
        nas[i] = (n < NN) ? na[n * 4 + t] : 0.f;
    }
    __syncthreads();

    const int g = tid >> 5, c = tid & 31;
    float nav[8][4];
    #pragma unroll
    for (int j = 0; j < 8; ++j)
        #pragma unroll
        for (int t = 0; t < 4; ++t) nav[j][t] = nas[(g * 8 + j) * 4 + t];

    float acc[3][8];
    #pragma unroll
    for (int cc = 0; cc < 3; ++cc)
        #pragma unroll
        for (int j = 0; j < 8; ++j) acc[cc][j] = 0.f;

    for (int u = 0; u < 32; ++u) {
        float aj[8];
        #pragma unroll
        for (int j = 0; j < 8; ++j) aj[j] = x0s[(g * 8 + j) * 32 + u];
        #pragma unroll
        for (int t = 0; t < 4; ++t) {
            float b0 = B[(u * 4 + t) * 96 + c];
            float b1 = B[(u * 4 + t) * 96 + 32 + c];
            float b2 = B[(u * 4 + t) * 96 + 64 + c];
            #pragma unroll
            for (int j = 0; j < 8; ++j) {
                float p = aj[j] * nav[j][t];
                acc[0][j] += p * b0;
                acc[1][j] += p * b1;
                acc[2][j] += p * b2;
            }
        }
    }

    const float inv_sc = 0.08838834764831845f;  // 1/sqrt(128)
    #pragma unroll
    for (int j = 0; j < 8; ++j) {
        int n = nodeBase + g * 8 + j;
        if (n < NN) {
            #pragma unroll
            for (int cc = 0; cc < 3; ++cc)
                sc[((long)cc * NN + n) * 32 + c] = acc[cc][j] * inv_sc;
        }
    }
}

// ---------------------------------------------------------------------------
// CSR build: histogram -> scan -> scatter ids.
// ---------------------------------------------------------------------------
__global__ __launch_bounds__(256) void hist_kernel(
    const int* __restrict__ ei, int* __restrict__ counts)
{
    int e = blockIdx.x * 256 + threadIdx.x;
    if (e < NE) atomicAdd(&counts[ei[NE + e]], 1);
}

__global__ __launch_bounds__(1024) void scan_kernel(
    const int* __restrict__ counts, int* __restrict__ offsets)
{
    __shared__ int partial[1024];
    const int t = threadIdx.x;
    const int base = t * 20;          // 1024*20 = 20480 >= NN
    int loc[20];
    int s = 0;
    #pragma unroll
    for (int i = 0; i < 20; ++i) {
        int v = (base + i < NN) ? counts[base + i] : 0;
        loc[i] = s;
        s += v;
    }
    partial[t] = s;
    __syncthreads();
    for (int off = 1; off < 1024; off <<= 1) {
        int v = (t >= off) ? partial[t - off] : 0;
        __syncthreads();
        partial[t] += v;
        __syncthreads();
    }
    int pre = (t == 0) ? 0 : partial[t - 1];
    #pragma unroll
    for (int i = 0; i < 20; ++i)
        if (base + i <= NN) offsets[base + i] = pre + loc[i];
}

__global__ __launch_bounds__(256) void scatter_ids(
    const int* __restrict__ ei, const int* __restrict__ offsets,
    int* __restrict__ cursor, int* __restrict__ sidx)
{
    int e = blockIdx.x * 256 + threadIdx.x;
    if (e < NE) {
        int d = ei[NE + e];
        int pos = offsets[d] + atomicAdd(&cursor[d], 1);
        sidx[pos] = e;
    }
}

// ---------------------------------------------------------------------------
// Kernel B1 (MFMA): w = silu(ee@Wm0/sqrt8) @ Wm1 * 0.125, bf16 MFMA.
// Block = 64 SORTED positions [b*64, b*64+64). Phase 1 computes h in fp32,
// writes bf16 directly in A-fragment order. Wm1 staged in B-fragment order
// (0.125 folded). Phase 2: wave wv owns edge-tile wv x 6 channel-tiles;
// 2 x mfma_f32_16x16x32_bf16 per tile (K=64). D routed through LDS ->
// coalesced packed-uint bf16x2 stores at sorted position.
// ---------------------------------------------------------------------------
__global__ __launch_bounds__(256) void edge_w(
    const float* __restrict__ ee,
    const int*   __restrict__ sidx,
    const float* __restrict__ Wm0,
    const float* __restrict__ Wm1,
    unsigned int* __restrict__ w)
{
    __shared__ float ees[64 * 8];                 // [e*8 + k]
    __shared__ float wm0s[512];                   // [k*64 + i]
    __shared__ unsigned short hsf[8 * 64 * 8];    // A-frags: [(tile*2+kh)*64+lane]*8+j
    __shared__ unsigned short wm1f[12 * 64 * 8];  // B-frags: [(kh*6+nt)*64+lane]*8+j
    __shared__ unsigned short wtile[64 * 96];     // D tile, row-major shorts

    const int tid = threadIdx.x;
    const long pb = (long)blockIdx.x * 64;        // sorted position base

    for (int i = tid; i < 512; i += 256) wm0s[i] = Wm0[i];
    // gathered ee staging: 8 consecutive threads read one 32B row
    for (int i = tid; i < 512; i += 256) {
        int le = i >> 3, k = i & 7;
        int e = sidx[pb + le];
        ees[i] = ee[(long)e * 8 + k];
    }
    // Wm1 -> B-fragment order, bf16, fold 0.125
    for (int idx = tid; idx < 6144; idx += 256) {
        int j = idx & 7, lane = (idx >> 3) & 63, sec = idx >> 9;
        int kh = sec / 6, nt = sec % 6;
        int k = kh * 32 + ((lane >> 4) * 8) + j;
        int n = nt * 16 + (lane & 15);
        wm1f[idx] = f2bf16(Wm1[k * 96 + n] * 0.125f);
    }
    __syncthreads();

    // phase 1: h[e][k] = silu((ee[e].Wm0[:,k])/sqrt8), bf16 into A-frag slots
    {
        const float inv_sqrt8 = 0.35355339059327373f;
        const int e = tid >> 2, i0 = (tid & 3) * 16;
        const int tile = e >> 4, m = e & 15;
        float emb[8];
        #pragma unroll
        for (int k = 0; k < 8; ++k) emb[k] = ees[e * 8 + k];
        #pragma unroll
        for (int i = 0; i < 16; ++i) {
            int k = i0 + i;
            float t = 0.f;
            #pragma unroll
            for (int q = 0; q < 8; ++q) t += emb[q] * wm0s[q * 64 + k];
            int kh = k >> 5, kq = (k >> 3) & 3, j = k & 7;
            int lane = kq * 16 + m;
            hsf[((tile * 2 + kh) * 64 + lane) * 8 + j] = f2bf16(silu_f(t * inv_sqrt8));
        }
    }
    __syncthreads();

    // phase 2: MFMA. wave wv -> edge-tile wv; loop 6 channel-tiles.
    {
        const int wv = tid >> 6, lane = tid & 63;
        const short8v a0 = *(const short8v*)&hsf[((wv * 2 + 0) * 64 + lane) * 8];
        const short8v a1 = *(const short8v*)&hsf[((wv * 2 + 1) * 64 + lane) * 8];
        const int col = lane & 15, rowq = (lane >> 4) * 4;
        #pragma unroll
        for (int nt = 0; nt < 6; ++nt) {
            short8v b0 = *(const short8v*)&wm1f[((0 * 6 + nt) * 64 + lane) * 8];
            short8v b1 = *(const short8v*)&wm1f[((1 * 6 + nt) * 64 + lane) * 8];
            float4v acc = {0.f, 0.f, 0.f, 0.f};
            acc = __builtin_amdgcn_mfma_f32_16x16x32_bf16(a0, b0, acc, 0, 0, 0);
            acc = __builtin_amdgcn_mfma_f32_16x16x32_bf16(a1, b1, acc, 0, 0, 0);
            const int c = nt * 16 + col;
            #pragma unroll
            for (int r = 0; r < 4; ++r)
                wtile[(wv * 16 + rowq + r) * 96 + c] = f2bf16(acc[r]);
        }
    }
    __syncthreads();

    // copy-out: 64 rows x 48 uints, coalesced
    const unsigned int* wt = (const unsigned int*)wtile;
    for (int i = tid; i < 3072; i += 256) {
        int row = i / 48, q = i % 48;
        w[(pb + row) * 48 + q] = wt[row * 48 + q];
    }
}

// ---------------------------------------------------------------------------
// Kernel B2: single-pass atomic-free gather-reduce. w rows indexed by SORTED
// position j -> sequential streaming. yAll plane-major -> lane-coalesced.
// ---------------------------------------------------------------------------
__global__ __launch_bounds__(256) void gather_reduce(
    const unsigned int* __restrict__ w,
    const float* __restrict__ ea,
    const int*   __restrict__ ei,
    const float* __restrict__ yAll,
    const int*   __restrict__ sidx,
    const int*   __restrict__ offsets,
    float* __restrict__ mid)
{
    const int tid = threadIdx.x;
    const int n = blockIdx.x * 8 + (tid >> 5);
    const int u = tid & 31;
    if (n >= NN) return;

    const int lo = offsets[n], hi = offsets[n + 1];

    const float invAVG = 0.17677669529663687f;                        // 1/sqrt(32)
    const float c1     = 0.5773502691896258f * 0.17677669529663687f;  // /sqrt3/sqrt32
    const float c2     = 0.4472135954999579f * 0.17677669529663687f;  // /sqrt5/sqrt32

    const int p = u >> 1;
    const bool odd = (u & 1);

    float acc0 = 0.f, acc1 = 0.f, acc2 = 0.f;
    #pragma unroll 2
    for (int j = lo; j < hi; ++j) {
        const int e = sidx[j];                 // broadcast within group
        const int s = ei[e];                   // broadcast
        const unsigned int* wr = w + (long)j * 48;
        const float* eav = ea + (long)e * 9;
        const float* yb  = yAll + (long)s * 288;

        unsigned int v0 = wr[p];
        unsigned int v1 = wr[16 + p];
        unsigned int v2 = wr[32 + p];
        float w0 = odd ? __uint_as_float(v0 & 0xffff0000u) : __uint_as_float(v0 << 16);
        float w1 = odd ? __uint_as_float(v1 & 0xffff0000u) : __uint_as_float(v1 << 16);
        float w2 = odd ? __uint_as_float(v2 & 0xffff0000u) : __uint_as_float(v2 << 16);

        acc0 += w0 * yb[u] * eav[0];

        float d1 = yb[32 + 0 * 32 + u] * eav[1]
                 + yb[32 + 1 * 32 + u] * eav[2]
                 + yb[32 + 2 * 32 + u] * eav[3];
        acc1 += w1 * d1;

        float d2 = yb[128 + 0 * 32 + u] * eav[4]
                 + yb[128 + 1 * 32 + u] * eav[5]
                 + yb[128 + 2 * 32 + u] * eav[6]
                 + yb[128 + 3 * 32 + u] * eav[7]
                 + yb[128 + 4 * 32 + u] * eav[8];
        acc2 += w2 * d2;
    }

    float* midRow = mid + (long)n * 96;
    midRow[u]      = acc0 * invAVG;
    midRow[32 + u] = acc1 * c1;
    midRow[64 + u] = acc2 * c2;
}

// ---------------------------------------------------------------------------
// Kernel C: output GEMV + sc + silu.
// ---------------------------------------------------------------------------
__global__ __launch_bounds__(256) void node_out(
    const float* __restrict__ mid,
    const float* __restrict__ sc,
    const float* __restrict__ L0,
    const float* __restrict__ L1,
    const float* __restrict__ L2,
    float* __restrict__ out)
{
    __shared__ float l0[32 * 32];
    __shared__ float l1[64 * 32];
    __shared__ float l2[96 * 32];
    __shared__ float ms[8][96];
    const int tid = threadIdx.x;
    const int nodeBase = blockIdx.x * 8;

    for (int i = tid; i < 1024; i += 256) l0[i] = L0[i];
    for (int i = tid; i < 2048; i += 256) l1[i] = L1[i];
    for (int i = tid; i < 3072; i += 256) l2[i] = L2[i];
    for (int i = tid; i < 768; i += 256) {
        int nl = i / 96, c = i % 96;
        int n = nodeBase + nl;
        ms[nl][c] = (n < NN) ? mid[(long)n * 96 + c] : 0.f;
    }
    __syncthreads();

    const int nl = tid >> 5, wv = tid & 31;
    const int n = nodeBase + nl;
    if (n >= NN) return;

    float a0 = 0.f, a1 = 0.f, a2 = 0.f;
    #pragma unroll
    for (int u = 0; u < 32; ++u) {
        float m = ms[nl][u];
        a0 += m * l0[u * 32 + wv];
        a1 += m * l1[u * 32 + wv];
        a2 += m * l2[u * 32 + wv];
    }
    #pragma unroll
    for (int u = 32; u < 64; ++u) {
        float m = ms[nl][u];
        a1 += m * l1[u * 32 + wv];
        a2 += m * l2[u * 32 + wv];
    }
    #pragma unroll
    for (int u = 64; u < 96; ++u) a2 += ms[nl][u] * l2[u * 32 + wv];

    const float is32 = 0.17677669529663687f;
    const float is64 = 0.125f;
    const float is96 = 0.10206207261596575f;
    const long base = (long)n * 32 + wv;
    out[base]                     = silu_f(a0 * is32 + sc[base]);
    out[(long)NN * 32 + base]     = silu_f(a1 * is64 + sc[(long)NN * 32 + base]);
    out[(long)2 * NN * 32 + base] = silu_f(a2 * is96 + sc[(long)2 * NN * 32 + base]);
}

extern "C" void kernel_launch(void* const* d_in, const int* in_sizes, int n_in,
                              void* d_out, int out_size, void* d_ws, size_t ws_size,
                              hipStream_t stream)
{
    const float* x   = (const float*)d_in[0];
    const float* na  = (const float*)d_in[1];
    const float* ee  = (const float*)d_in[2];
    const float* ea  = (const float*)d_in[3];
    const int*   ei  = (const int*)d_in[4];
    const float* W10 = (const float*)d_in[5];
    const float* W11 = (const float*)d_in[6];
    const float* W12 = (const float*)d_in[7];
    const float* Wm0 = (const float*)d_in[8];
    const float* Wm1 = (const float*)d_in[9];
    const float* L0  = (const float*)d_in[10];
    const float* L1  = (const float*)d_in[11];
    const float* L2  = (const float*)d_in[12];
    const float* scW = (const float*)d_in[13];
    float* out = (float*)d_out;

    float* yAll    = (float*)d_ws;                  // NN*288 f32
    float* sc      = yAll + (size_t)NN * 288;       // 3*NN*32 f32
    float* mid     = sc + (size_t)3 * NN * 32;      // NN*96 f32
    int*   counts  = (int*)(mid + (size_t)NN * 96); // NN
    int*   offsets = counts + NN;                   // NN+1
    int*   cursor  = offsets + NN + 1;              // NN
    int*   sidx    = cursor + NN;                   // NE
    unsigned int* wbuf = (unsigned int*)(sidx + NE);// NE*48 uints (123 MB)

    hipMemsetAsync(counts, 0, NN * sizeof(int), stream);
    hipMemsetAsync(cursor, 0, NN * sizeof(int), stream);

    hist_kernel<<<(NE + 255) / 256, 256, 0, stream>>>(ei, counts);
    scan_kernel<<<1, 1024, 0, stream>>>(counts, offsets);
    scatter_ids<<<(NE + 255) / 256, 256, 0, stream>>>(ei, offsets, cursor, sidx);

    node_y<<<(NN + 7) / 8, 256, 0, stream>>>(x, W10, W11, W12, yAll);
    node_sc<<<(NN + 63) / 64, 256, 0, stream>>>(x, na, scW, sc);

    edge_w<<<NE / 64, 256, 0, stream>>>(ee, sidx, Wm0, Wm1, wbuf);
    gather_reduce<<<(NN + 7) / 8, 256, 0, stream>>>(wbuf, ea, ei, yAll, sidx,
                                                    offsets, mid);

    node_out<<<(NN + 7) / 8, 256, 0, stream>>>(mid, sc, L0, L1, L2, out);
}